// Round 2
// 93.483 us; speedup vs baseline: 1.1862x; 1.1862x over previous
//
#include <hip/hip_runtime.h>

// Feature-hashing scatter: out[b, mask[i]] += signs[i] * x[b, i]
// B=256, F=524288, O=16384.
// R3: native ds_add_u32 fixed-point accumulation -> 113.8 us.
// R4: software-pipelined load/drain double-buffer -> 110.9 us.
// R5/R6: 16B pm loads via permuted pack layout (-25% VMEM instrs),
//     nontemporal x loads / out stores (via ext_vector_type -- HIP float4
//     is rejected by the nontemporal builtins), vectorized LDS init+writeout.

#define F_IN   524288
#define N_OUT  16384
#define NB     256
#define BLOCK  1024
#define HBS    2                    // pipeline stages per buffer (8 feats/stage)
#define ITERS8 (F_IN / 8 / BLOCK)   // 64 stages total

#define FP_SCALE     1048576.0f            // 2^20
#define FP_INV_SCALE 9.5367431640625e-07f  // 2^-20

typedef float        f32x4 __attribute__((ext_vector_type(4)));
typedef unsigned int u32x4 __attribute__((ext_vector_type(4)));
typedef int          i32x4 __attribute__((ext_vector_type(4)));

// ---------------------------------------------------------------------------
// pack_kernel: build a PERMUTED packed-mask array so the hash kernel's three
// streams are all 16B lane-contiguous loads. u32x4 element g (= s*1024+tid)
// holds 8 ushorts: the 4 features of quad q0 = s*2048+tid (x-load A) in
// .x/.y and the 4 features of quad q1 = q0+1024 (x-load B) in .z/.w.
// ushort layout: bin[13:0] | sign<<15.
// ---------------------------------------------------------------------------
__device__ __forceinline__ unsigned pk2(int m0, float s0, int m1, float s1) {
    unsigned u0 = ((unsigned)m0 & 0x3FFFu) | ((__float_as_uint(s0) >> 31) << 15);
    unsigned u1 = ((unsigned)m1 & 0x3FFFu) | ((__float_as_uint(s1) >> 31) << 15);
    return u0 | (u1 << 16);
}

__global__ void pack_kernel(const float* __restrict__ signs,
                            const int* __restrict__ mask,
                            u32x4* __restrict__ pmp) {
    const int g = blockIdx.x * blockDim.x + threadIdx.x;   // 65536 threads
    const int s   = g >> 10;
    const int tid = g & 1023;
    const int q0 = s * 2048 + tid;
    const int q1 = q0 + 1024;

    const i32x4* m4 = (const i32x4*)mask;
    const f32x4* s4 = (const f32x4*)signs;
    const i32x4 ma = m4[q0], mb = m4[q1];
    const f32x4 sa = s4[q0], sb = s4[q1];

    u32x4 o;
    o.x = pk2(ma.x, sa.x, ma.y, sa.y);
    o.y = pk2(ma.z, sa.z, ma.w, sa.w);
    o.z = pk2(mb.x, sb.x, mb.y, sb.y);
    o.w = pk2(mb.z, sb.z, mb.w, sb.w);
    pmp[g] = o;
}

// ---------------------------------------------------------------------------
// hash_kernel: one block per batch row, 16384-bin fixed-point histogram in
// LDS, ds_add_u32 accumulation, software-pipelined 2-deep.
// ---------------------------------------------------------------------------
__device__ __forceinline__ int to_fixed(float v, unsigned p) {
    // XOR the fp32 sign bit with packed bit15, scale to fixed point.
    float s = __uint_as_float(__float_as_uint(v) ^ ((p & 0x8000u) << 16));
    return __float2int_rn(s * FP_SCALE);
}

__device__ __forceinline__ void acc2(int* __restrict__ hist, unsigned pp,
                                     float v0, float v1) {
    atomicAdd(&hist[pp & 0x3FFFu], to_fixed(v0, pp));
    const unsigned p1 = pp >> 16;
    atomicAdd(&hist[p1 & 0x3FFFu], to_fixed(v1, p1));
}

__global__ __launch_bounds__(BLOCK, 1)
void hash_kernel(const float* __restrict__ x,
                 const u32x4* __restrict__ pmp,
                 float* __restrict__ out) {
    __shared__ int hist[N_OUT];   // 64 KB

    const int tid = threadIdx.x;
    const int b = blockIdx.x;

    // Vectorized zero-init (4 i32x4 stores per thread).
    i32x4* __restrict__ h4 = (i32x4*)hist;
    #pragma unroll
    for (int k = tid; k < N_OUT / 4; k += BLOCK) h4[k] = (i32x4)0;
    __syncthreads();

    const f32x4* __restrict__ x4 = (const f32x4*)(x + (size_t)b * F_IN);

    // Double-buffered registers: buffer A = (xa_,xb_,ma_), B = (ya_,yb_,mb_).
    f32x4 xa_[HBS], xb_[HBS], ya_[HBS], yb_[HBS];
    u32x4 ma_[HBS], mb_[HBS];

#define LOAD(XA, XB, M, IT)                                                     \
    _Pragma("unroll")                                                           \
    for (int j = 0; j < HBS; ++j) {                                             \
        const int s = (IT) + j;                                                 \
        (XA)[j] = __builtin_nontemporal_load(&x4[s * 2 * BLOCK + tid]);         \
        (XB)[j] = __builtin_nontemporal_load(&x4[s * 2 * BLOCK + BLOCK + tid]); \
        (M)[j]  = pmp[s * BLOCK + tid];                                         \
    }

#define DRAIN(XA, XB, M)                                  \
    _Pragma("unroll")                                     \
    for (int j = 0; j < HBS; ++j) {                       \
        acc2(hist, (M)[j].x, (XA)[j].x, (XA)[j].y);       \
        acc2(hist, (M)[j].y, (XA)[j].z, (XA)[j].w);       \
        acc2(hist, (M)[j].z, (XB)[j].x, (XB)[j].y);       \
        acc2(hist, (M)[j].w, (XB)[j].z, (XB)[j].w);       \
    }

    // Software pipeline: while draining one buffer, the other buffer's
    // loads are in flight (LDS atomics hide under HBM latency).
    LOAD(xa_, xb_, ma_, 0);
    #pragma unroll 1
    for (int it = 0; it < ITERS8 - 2 * HBS; it += 2 * HBS) {
        LOAD(ya_, yb_, mb_, it + HBS);
        DRAIN(xa_, xb_, ma_);
        LOAD(xa_, xb_, ma_, it + 2 * HBS);
        DRAIN(ya_, yb_, mb_);
    }
    LOAD(ya_, yb_, mb_, ITERS8 - HBS);
    DRAIN(xa_, xb_, ma_);
    DRAIN(ya_, yb_, mb_);

#undef LOAD
#undef DRAIN

    __syncthreads();

    // Coalesced vectorized row write-out with fixed->float conversion
    // (fully overwrites out; no pre-zero needed). NT store: never re-read.
    f32x4* __restrict__ o4 = (f32x4*)(out + (size_t)b * N_OUT);
    #pragma unroll
    for (int k = tid; k < N_OUT / 4; k += BLOCK) {
        const i32x4 h = h4[k];
        f32x4 f;
        f.x = (float)h.x * FP_INV_SCALE;
        f.y = (float)h.y * FP_INV_SCALE;
        f.z = (float)h.z * FP_INV_SCALE;
        f.w = (float)h.w * FP_INV_SCALE;
        __builtin_nontemporal_store(f, &o4[k]);
    }
}

extern "C" void kernel_launch(void* const* d_in, const int* in_sizes, int n_in,
                              void* d_out, int out_size, void* d_ws, size_t ws_size,
                              hipStream_t stream) {
    const float* x     = (const float*)d_in[0];
    const float* signs = (const float*)d_in[1];
    const int*   mask  = (const int*)d_in[2];
    float*       out   = (float*)d_out;

    u32x4* pmp = (u32x4*)d_ws;   // 1 MB permuted packed mask
    pack_kernel<<<(F_IN / 8 + 255) / 256, 256, 0, stream>>>(signs, mask, pmp);
    hash_kernel<<<NB, BLOCK, 0, stream>>>(x, pmp, out);
}